// Round 14
// baseline (207.440 us; speedup 1.0000x reference)
//
#include <hip/hip_runtime.h>
#include <hip/hip_bf16.h>
#include <hip/hip_fp16.h>

typedef _Float16 half8 __attribute__((ext_vector_type(8)));
typedef _Float16 half4_t __attribute__((ext_vector_type(4)));
typedef _Float16 h2 __attribute__((ext_vector_type(2)));
typedef float f32x4 __attribute__((ext_vector_type(4)));
typedef unsigned int u32;

#define NEG_SLOPE 0.2f
#define SELU_SCALE 1.0507009873554805f
#define SELU_ALPHA 1.6732632423543772f
#define LOG2E 1.4426950408889634f
#define DEFER_THR 4.0f

#if __has_builtin(__builtin_amdgcn_fdot2)
#define FDOT2(a, b, c) __builtin_amdgcn_fdot2((a), (b), (c), false)
#else
static __device__ inline float FDOT2(h2 a, h2 b, float c) {
    return c + (float)a[0] * (float)b[0] + (float)a[1] * (float)b[1];
}
#endif

static __device__ inline h2 h2max(h2 a, h2 b) {
#if __has_builtin(__builtin_elementwise_max)
    return __builtin_elementwise_max(a, b);
#else
    h2 r; r[0] = a[0] > b[0] ? a[0] : b[0]; r[1] = a[1] > b[1] ? a[1] : b[1]; return r;
#endif
}

static __device__ inline h2 shfl_h2(h2 v, int d) {
    u32 u = __builtin_bit_cast(u32, v);
    return __builtin_bit_cast(h2, (u32)__shfl_xor((int)u, d, 64));
}

// raw v_exp_f32: D = 2^S0 (flushes to 0 for very negative inputs)
static __device__ inline float fexp2(float x) {
    float r;
    asm("v_exp_f32 %0, %1" : "=v"(r) : "v"(x));
    return r;
}

static __device__ inline h2 pk2(float a) {
#if __has_builtin(__builtin_amdgcn_cvt_pkrtz)
    return __builtin_bit_cast(h2, __builtin_amdgcn_cvt_pkrtz(a, a));
#else
    _Float16 h = (_Float16)a; return (h2){h, h};
#endif
}

// ---------------- shared GEMM tile body (128 rows starting at row0) --------
static __device__ inline void gemm_tile(
    const float* __restrict__ x, const float* __restrict__ Wl,
    const float* __restrict__ Wr, _Float16* __restrict__ glA,
    _Float16* __restrict__ glB, int n_nodes, int row0, float* xs)
{
    if (row0 >= n_nodes) return;
    {
        int t = threadIdx.x;
        #pragma unroll
        for (int i = 0; i < 8; i++) {
            int idx = t + i * 256;           // 2048 float4 total
            int r = idx >> 4, c = (idx & 15) * 4;
            int row = row0 + r;
            f32x4 v = (f32x4){0.f, 0.f, 0.f, 0.f};
            if (row < n_nodes) v = *(const f32x4*)(x + (size_t)row * 64 + c);
            *(f32x4*)(xs + r * 68 + c) = v;
        }
    }
    __syncthreads();

    int wid  = threadIdx.x >> 6;
    int lane = threadIdx.x & 63;
    int l15  = lane & 15;
    int g    = lane >> 4;
    int kb   = g * 8;
    int colbase = wid * 192;

    half8 bw0[12], bw1[12];
    #pragma unroll
    for (int t = 0; t < 12; t++) {
        int col = colbase + t * 16 + l15;
        const float* wcol = (col < 384) ? (Wl + col) : (Wr + (col - 384));
        #pragma unroll
        for (int j = 0; j < 8; j++) {
            bw0[t][j] = (_Float16)wcol[(size_t)(kb + j) * 384];
            bw1[t][j] = (_Float16)wcol[(size_t)(32 + kb + j) * 384];
        }
    }

    #pragma unroll
    for (int rt = 0; rt < 8; rt++) {
        int r0 = rt * 16;
        half8 a0, a1;
        #pragma unroll
        for (int j = 0; j < 8; j++) {
            a0[j] = (_Float16)xs[(r0 + l15) * 68 + kb + j];
            a1[j] = (_Float16)xs[(r0 + l15) * 68 + 32 + kb + j];
        }
        int nodeRow = row0 + r0 + l15;
        #pragma unroll
        for (int t = 0; t < 12; t++) {
            f32x4 acc = (f32x4){0.f, 0.f, 0.f, 0.f};
            acc = __builtin_amdgcn_mfma_f32_16x16x32_f16(bw0[t], a0, acc, 0, 0, 0);
            acc = __builtin_amdgcn_mfma_f32_16x16x32_f16(bw1[t], a1, acc, 0, 0, 0);
            if (nodeRow < n_nodes) {
                int c0 = colbase + t * 16 + g * 4;
                half4_t hv;
                #pragma unroll
                for (int r = 0; r < 4; r++) hv[r] = (_Float16)acc[r];
                _Float16* dst = (c0 < 384)
                    ? (glA + (size_t)nodeRow * 384 + c0)
                    : (glB + (size_t)nodeRow * 384 + (c0 - 384));
                *(half4_t*)dst = hv;
            }
        }
    }
}

// ---------------- Fused: GEMM part 1 (blocks < nbG1) + dst histogram -------
__global__ __launch_bounds__(256) void gemm_hist_kernel(
    const float* __restrict__ x, const float* __restrict__ Wl,
    const float* __restrict__ Wr, _Float16* __restrict__ glA,
    _Float16* __restrict__ glB, int n_nodes,
    const int* __restrict__ eidx, int* __restrict__ count, int n_edges,
    int nbG1)
{
    __shared__ float xs[128 * 68];
    if ((int)blockIdx.x >= nbG1) {
        int i0 = (((int)blockIdx.x - nbG1) * 256 + (int)threadIdx.x) * 4;
        if (i0 + 3 < n_edges) {
            int4 d4 = *(const int4*)(eidx + (size_t)n_edges + i0);
            atomicAdd(&count[d4.x], 1);
            atomicAdd(&count[d4.y], 1);
            atomicAdd(&count[d4.z], 1);
            atomicAdd(&count[d4.w], 1);
        } else {
            for (int k = 0; k < 4; k++)
                if (i0 + k < n_edges)
                    atomicAdd(&count[eidx[(size_t)n_edges + i0 + k]], 1);
        }
        return;
    }
    gemm_tile(x, Wl, Wr, glA, glB, n_nodes, blockIdx.x * 128, xs);
}

// local scan of 1024-node chunks (value = deg = count+1) + per-block LDS
// degree histogram (bin = 255 - min(deg,255), i.e. descending degree)
__global__ __launch_bounds__(256) void scan_local_kernel(
    const int* __restrict__ count, int* __restrict__ row_ptr,
    int* __restrict__ blksum, int* __restrict__ blockhist, int n)
{
    __shared__ int ws[4];
    __shared__ int dh[256];
    int blk = blockIdx.x, t = threadIdx.x;
    dh[t] = 0;
    __syncthreads();

    int base = blk * 1024 + t * 4;
    int d0 = (base + 0 < n) ? count[base + 0] + 1 : 0;
    int d1 = (base + 1 < n) ? count[base + 1] + 1 : 0;
    int d2 = (base + 2 < n) ? count[base + 2] + 1 : 0;
    int d3 = (base + 3 < n) ? count[base + 3] + 1 : 0;
    if (d0) atomicAdd(&dh[255 - (d0 < 255 ? d0 : 255)], 1);
    if (d1) atomicAdd(&dh[255 - (d1 < 255 ? d1 : 255)], 1);
    if (d2) atomicAdd(&dh[255 - (d2 < 255 ? d2 : 255)], 1);
    if (d3) atomicAdd(&dh[255 - (d3 < 255 ? d3 : 255)], 1);

    int tsum = d0 + d1 + d2 + d3;
    int lane = t & 63, wid = t >> 6;
    int s = tsum;
    #pragma unroll
    for (int d = 1; d < 64; d <<= 1) {
        int u = __shfl_up(s, d, 64);
        if (lane >= d) s += u;
    }
    if (lane == 63) ws[wid] = s;
    __syncthreads();
    int woff = 0;
    #pragma unroll
    for (int w = 0; w < 4; w++) if (w < wid) woff += ws[w];
    int excl = woff + s - tsum;
    if (base + 0 < n) row_ptr[base + 0] = excl;
    if (base + 1 < n) row_ptr[base + 1] = excl + d0;
    if (base + 2 < n) row_ptr[base + 2] = excl + d0 + d1;
    if (base + 3 < n) row_ptr[base + 3] = excl + d0 + d1 + d2;
    if (t == 255) blksum[blk] = woff + s;
    __syncthreads();
    blockhist[blk * 256 + t] = dh[t];
}

// merged: (a) exclusive scan of blksum (<=64 chunks, wave 0) + total ->
// row_ptr[n]; (b) blockhist -> absolute exclusive offsets per (bin, blk)
__global__ __launch_bounds__(256) void binscan_kernel(
    int* __restrict__ blockhist, int* __restrict__ blksum,
    int* __restrict__ row_ptr, int nblk, int n)
{
    __shared__ int ws[4];
    int b = threadIdx.x;

    if (b < 64) {
        int v = (b < nblk) ? blksum[b] : 0;
        int s = v;
        #pragma unroll
        for (int d = 1; d < 64; d <<= 1) {
            int u = __shfl_up(s, d, 64);
            if (b >= d) s += u;
        }
        if (b < nblk) blksum[b] = s - v;
        if (b == 63) row_ptr[n] = s;
    }

    int vals[64];
    #pragma unroll
    for (int blk = 0; blk < 64; blk++)
        vals[blk] = (blk < nblk) ? blockhist[blk * 256 + b] : 0;
    int run = 0;
    #pragma unroll
    for (int blk = 0; blk < 64; blk++) {
        int x = vals[blk];
        vals[blk] = run;
        run += x;
    }
    int lane = b & 63, wid = b >> 6;
    int s = run;
    #pragma unroll
    for (int d = 1; d < 64; d <<= 1) {
        int u = __shfl_up(s, d, 64);
        if (lane >= d) s += u;
    }
    if (lane == 63) ws[wid] = s;
    __syncthreads();
    int woff = 0;
    #pragma unroll
    for (int w = 0; w < 4; w++) if (w < wid) woff += ws[w];
    int basep = woff + s - run;
    #pragma unroll
    for (int blk = 0; blk < 64; blk++)
        if (blk < nblk) blockhist[blk * 256 + b] = vals[blk] + basep;
}

// fused: finalize row_ptr, init cursor, seed self-loop, counting-sort placement
__global__ __launch_bounds__(256) void cursor_order_kernel(
    int* __restrict__ row_ptr, const int* __restrict__ blksum,
    const int* __restrict__ count, const int* __restrict__ blockhist,
    int* __restrict__ cursor, int* __restrict__ sorted_src,
    int* __restrict__ order, int n)
{
    __shared__ int loff[256];
    int blk = blockIdx.x, t = threadIdx.x;
    loff[t] = blockhist[blk * 256 + t];
    __syncthreads();
    int base = blk * 1024 + t * 4;
    #pragma unroll
    for (int i = 0; i < 4; i++) {
        int node = base + i;
        if (node < n) {
            int rp = row_ptr[node] + blksum[node >> 10];
            row_ptr[node] = rp;
            cursor[node] = rp + 1;       // slot rp reserved for self-loop
            sorted_src[rp] = node;
            int deg = count[node] + 1;
            int bin = 255 - (deg < 255 ? deg : 255);
            int pos = atomicAdd(&loff[bin], 1);
            order[pos] = node;
        }
    }
}

// ---------------- Fused: GEMM part 2 (blocks < nbG2) + CSR scatter ---------
__global__ __launch_bounds__(256) void gemm_scatter_kernel(
    const float* __restrict__ x, const float* __restrict__ Wl,
    const float* __restrict__ Wr, _Float16* __restrict__ glA,
    _Float16* __restrict__ glB, int n_nodes, int rowBase,
    const int* __restrict__ eidx, int* __restrict__ cursor,
    int* __restrict__ sorted_src, int n_edges, int nbG2)
{
    __shared__ float xs[128 * 68];
    if ((int)blockIdx.x >= nbG2) {
        int i0 = (((int)blockIdx.x - nbG2) * 256 + (int)threadIdx.x) * 4;
        if (i0 + 3 < n_edges) {
            int4 s4 = *(const int4*)(eidx + i0);
            int4 d4 = *(const int4*)(eidx + (size_t)n_edges + i0);
            int p0 = atomicAdd(&cursor[d4.x], 1); sorted_src[p0] = s4.x;
            int p1 = atomicAdd(&cursor[d4.y], 1); sorted_src[p1] = s4.y;
            int p2 = atomicAdd(&cursor[d4.z], 1); sorted_src[p2] = s4.z;
            int p3 = atomicAdd(&cursor[d4.w], 1); sorted_src[p3] = s4.w;
        } else {
            for (int k = 0; k < 4; k++) {
                int i = i0 + k;
                if (i < n_edges) {
                    int d = eidx[(size_t)n_edges + i];
                    int s = eidx[i];
                    int pos = atomicAdd(&cursor[d], 1);
                    sorted_src[pos] = s;
                }
            }
        }
        return;
    }
    gemm_tile(x, Wl, Wr, glA, glB, n_nodes, rowBase + blockIdx.x * 128, xs);
}

// ---------------- Edge phase: 16-lane group per dst node, 1-deep prefetch ----
// Pair-octet layout on 768B rows: lane l0 owns bytes P*256 + l0*16 (P=0..2).
// oct=l0>>3 -> head 2P+oct; q=l0&7 -> f=q*8..q*8+7. 3 heads/lane.
// Nodes processed in descending-degree order (order[]).
__global__ __launch_bounds__(256) void edge_kernel(
    const _Float16* __restrict__ glA,     // [n][384] source-side projection
    const _Float16* __restrict__ glB,     // [n][384] target-side projection
    const int* __restrict__ row_ptr,
    const int* __restrict__ sorted_src,
    const int* __restrict__ order,
    const float* __restrict__ att,        // [6][64]
    const float* __restrict__ bias,       // [64]
    float* __restrict__ out, int n_nodes)
{
    int tid  = blockIdx.x * 256 + threadIdx.x;
    int ggid = tid >> 4;                       // global 16-lane group id
    int GG   = (gridDim.x * 256) >> 4;
    int l0  = threadIdx.x & 15;
    int oct = l0 >> 3;
    int q   = l0 & 7;
    u32 l16 = (u32)l0 * 16u;

    const char* glA_b = (const char*)glA;
    const char* glB_b = (const char*)glB;
    const _Float16 c02 = (_Float16)NEG_SLOPE;

    h2 att_h[12];
    #pragma unroll
    for (int P = 0; P < 3; P++) {
        int h = 2 * P + oct;
        f32x4 av0 = *(const f32x4*)(att + h * 64 + q * 8);
        f32x4 av1 = *(const f32x4*)(att + h * 64 + q * 8 + 4);
        att_h[P * 4 + 0] = (h2){(_Float16)(av0[0] * LOG2E), (_Float16)(av0[1] * LOG2E)};
        att_h[P * 4 + 1] = (h2){(_Float16)(av0[2] * LOG2E), (_Float16)(av0[3] * LOG2E)};
        att_h[P * 4 + 2] = (h2){(_Float16)(av1[0] * LOG2E), (_Float16)(av1[1] * LOG2E)};
        att_h[P * 4 + 3] = (h2){(_Float16)(av1[2] * LOG2E), (_Float16)(av1[3] * LOG2E)};
    }
    f32x4 bv0 = *(const f32x4*)(bias + q * 8);
    f32x4 bv1 = *(const f32x4*)(bias + q * 8 + 4);

    for (int slot = ggid; slot < n_nodes; slot += GG) {
        int node = order[slot];

        h2 gr_h[12];
        {
            u32 rbase = (u32)node * 768u;
            #pragma unroll
            for (int P = 0; P < 3; P++) {
                half8 gv = *(const half8*)(glB_b + rbase + (u32)P * 256u + l16);
                gr_h[P * 4 + 0] = ((h2*)&gv)[0];
                gr_h[P * 4 + 1] = ((h2*)&gv)[1];
                gr_h[P * 4 + 2] = ((h2*)&gv)[2];
                gr_h[P * 4 + 3] = ((h2*)&gv)[3];
            }
        }

        float m[3], sden[3];
        h2 acc[12];
        #pragma unroll
        for (int P = 0; P < 3; P++) { m[P] = -1e30f; sden[P] = 0.f; }
        #pragma unroll
        for (int j = 0; j < 12; j++) acc[j] = (h2){(_Float16)0.f, (_Float16)0.f};

        int rp = row_ptr[node], re = row_ptr[node + 1];
        int reclamp = re - 1;

        auto lsrc = [&](int idx) {
            int ii = idx < reclamp ? idx : reclamp;
            return sorted_src[ii];
        };

        half8 A0, A1, A2, B0, B1, B2;

#define LOADX(X0, X1, X2, S)                                                 \
        {                                                                    \
            u32 o = (u32)(S) * 768u + l16;                                   \
            X0 = *(const half8*)(glA_b + o);                                 \
            X1 = *(const half8*)(glA_b + o + 256);                           \
            X2 = *(const half8*)(glA_b + o + 512);                           \
        }

// defer-max online softmax: rescale only when e exceeds m by > DEFER_THR
#define PROC1(X0, X1, X2)                                                    \
        {                                                                    \
            float e[3];                                                      \
            _Pragma("unroll")                                                \
            for (int P = 0; P < 3; P++) {                                    \
                h2 t0 = ((h2*)&X0)[0], t1 = ((h2*)&X0)[1],                   \
                   t2 = ((h2*)&X0)[2], t3 = ((h2*)&X0)[3];                   \
                if (P == 1) { t0 = ((h2*)&X1)[0]; t1 = ((h2*)&X1)[1];        \
                              t2 = ((h2*)&X1)[2]; t3 = ((h2*)&X1)[3]; }      \
                if (P == 2) { t0 = ((h2*)&X2)[0]; t1 = ((h2*)&X2)[1];        \
                              t2 = ((h2*)&X2)[2]; t3 = ((h2*)&X2)[3]; }      \
                t0 = t0 + gr_h[P * 4 + 0]; t1 = t1 + gr_h[P * 4 + 1];        \
                t2 = t2 + gr_h[P * 4 + 2]; t3 = t3 + gr_h[P * 4 + 3];        \
                t0 = h2max(t0, t0 * c02); t1 = h2max(t1, t1 * c02);          \
                t2 = h2max(t2, t2 * c02); t3 = h2max(t3, t3 * c02);          \
                e[P] = FDOT2(t3, att_h[P * 4 + 3], FDOT2(t2, att_h[P * 4 + 2],\
                       FDOT2(t1, att_h[P * 4 + 1], FDOT2(t0, att_h[P * 4 + 0],\
                       0.f))));                                              \
            }                                                                \
            _Pragma("unroll")                                                \
            for (int d = 1; d < 8; d <<= 1) {                                \
                e[0] += __shfl_xor(e[0], d, 64);                             \
                e[1] += __shfl_xor(e[1], d, 64);                             \
                e[2] += __shfl_xor(e[2], d, 64);                             \
            }                                                                \
            _Pragma("unroll")                                                \
            for (int P = 0; P < 3; P++) {                                    \
                if (e[P] > m[P] + DEFER_THR) {   /* rare rescale path */     \
                    float r = fexp2(m[P] - e[P]);                            \
                    sden[P] *= r;                                            \
                    h2 r2 = pk2(r);                                          \
                    acc[P * 4 + 0] = acc[P * 4 + 0] * r2;                    \
                    acc[P * 4 + 1] = acc[P * 4 + 1] * r2;                    \
                    acc[P * 4 + 2] = acc[P * 4 + 2] * r2;                    \
                    acc[P * 4 + 3] = acc[P * 4 + 3] * r2;                    \
                    m[P] = e[P];                                             \
                }                                                            \
                float p = fexp2(e[P] - m[P]);    /* <= 2^THR */              \
                sden[P] += p;                                                \
                h2 p2 = pk2(p);                                              \
                const h2* xv = (P == 0) ? (const h2*)&X0                     \
                             : (P == 1) ? (const h2*)&X1 : (const h2*)&X2;   \
                acc[P * 4 + 0] = acc[P * 4 + 0] + p2 * xv[0];                \
                acc[P * 4 + 1] = acc[P * 4 + 1] + p2 * xv[1];                \
                acc[P * 4 + 2] = acc[P * 4 + 2] + p2 * xv[2];                \
                acc[P * 4 + 3] = acc[P * 4 + 3] + p2 * xv[3];                \
            }                                                                \
        }

        {   // 1-deep pipeline (A/B alternate)
            LOADX(A0, A1, A2, sorted_src[rp]);
            int sN = lsrc(rp + 1);
            int idx = rp;
            for (;;) {
                LOADX(B0, B1, B2, sN);
                int sN2 = lsrc(idx + 2);
                PROC1(A0, A1, A2);
                idx++; if (idx >= re) break;
                LOADX(A0, A1, A2, sN2);
                sN = lsrc(idx + 2);
                PROC1(B0, B1, B2);
                idx++; if (idx >= re) break;
            }
        }
#undef PROC1
#undef LOADX

        h2 iv[3];
        #pragma unroll
        for (int P = 0; P < 3; P++) {
            float inv = 1.0f / (sden[P] + 1e-16f);
            _Float16 ih = (_Float16)inv;
            iv[P] = (h2){ih, ih};
        }
        float of[8];
        #pragma unroll
        for (int j = 0; j < 4; j++) {
            h2 o = acc[0 * 4 + j] * iv[0] + acc[1 * 4 + j] * iv[1] + acc[2 * 4 + j] * iv[2];
            o = o + shfl_h2(o, 8);       // partner octet: other 3 heads
            of[2 * j]     = (float)o[0];
            of[2 * j + 1] = (float)o[1];
        }

        if (l0 < 8) {                     // oct==0 lanes write the node row
            f32x4 ov0, ov1;
            #pragma unroll
            for (int k = 0; k < 4; k++) {
                float v0 = of[k] * (1.0f / 6.0f) + bv0[k];
                float v1 = of[k + 4] * (1.0f / 6.0f) + bv1[k];
                ov0[k] = (v0 > 0.f) ? SELU_SCALE * v0
                                    : SELU_SCALE * SELU_ALPHA * (__expf(v0) - 1.0f);
                ov1[k] = (v1 > 0.f) ? SELU_SCALE * v1
                                    : SELU_SCALE * SELU_ALPHA * (__expf(v1) - 1.0f);
            }
            float* op = out + (size_t)node * 64 + q * 8;
            *(f32x4*)op = ov0;
            *(f32x4*)(op + 4) = ov1;
        }
    }
}

// ---------------- launch ----------------
extern "C" void kernel_launch(void* const* d_in, const int* in_sizes, int n_in,
                              void* d_out, int out_size, void* d_ws, size_t ws_size,
                              hipStream_t stream) {
    const float* x    = (const float*)d_in[0];
    const int*   eidx = (const int*)d_in[1];
    const float* Wl   = (const float*)d_in[2];
    const float* Wr   = (const float*)d_in[3];
    const float* att  = (const float*)d_in[4];
    const float* bias = (const float*)d_in[5];
    float* out = (float*)d_out;

    int n = in_sizes[0] / 64;        // nodes
    int E = in_sizes[1] / 2;         // edges (pre-self-loop)
    int Et = E + n;
    int nblk = (n + 1023) / 1024;    // 49 for n=50000 (<= 64 required)

    char* w = (char*)d_ws;
    size_t off = 0;
    auto carve = [&](size_t bytes) {
        void* p = w + off;
        off = (off + bytes + 255) & ~(size_t)255;
        return p;
    };
    _Float16* glA   = (_Float16*)carve((size_t)n * 384 * sizeof(_Float16));
    _Float16* glB   = (_Float16*)carve((size_t)n * 384 * sizeof(_Float16));
    int* count      = (int*)carve((size_t)n * sizeof(int));
    int* row_ptr    = (int*)carve((size_t)(n + 1) * sizeof(int));
    int* cursor     = (int*)carve((size_t)n * sizeof(int));
    int* sorted_src = (int*)carve((size_t)Et * sizeof(int));
    int* order      = (int*)carve((size_t)n * sizeof(int));
    int* blksum     = (int*)carve(64 * sizeof(int));
    int* blockhist  = (int*)carve((size_t)nblk * 256 * sizeof(int));
    (void)ws_size;

    int nbG  = (n + 127) / 128;               // total gemm blocks
    int nbG1 = nbG / 2;                       // gemm blocks overlapped w/ hist
    int nbG2 = nbG - nbG1;                    // gemm blocks overlapped w/ scatter
    int rowBase = nbG1 * 128;
    int nbE4 = (E + 1023) / 1024;             // 4-edges/thread blocks

    hipMemsetAsync(count, 0, (size_t)n * sizeof(int), stream);
    hipLaunchKernelGGL(gemm_hist_kernel, dim3(nbG1 + nbE4), dim3(256), 0, stream,
                       x, Wl, Wr, glA, glB, n, eidx, count, E, nbG1);
    hipLaunchKernelGGL(scan_local_kernel, dim3(nblk), dim3(256), 0, stream,
                       count, row_ptr, blksum, blockhist, n);
    hipLaunchKernelGGL(binscan_kernel, dim3(1), dim3(256), 0, stream,
                       blockhist, blksum, row_ptr, nblk, n);
    hipLaunchKernelGGL(cursor_order_kernel, dim3(nblk), dim3(256), 0, stream,
                       row_ptr, blksum, count, blockhist, cursor, sorted_src,
                       order, n);
    hipLaunchKernelGGL(gemm_scatter_kernel, dim3(nbG2 + nbE4), dim3(256), 0, stream,
                       x, Wl, Wr, glA, glB, n, rowBase, eidx, cursor,
                       sorted_src, E, nbG2);
    hipLaunchKernelGGL(edge_kernel, dim3(2048), dim3(256), 0, stream,
                       glA, glB, row_ptr, sorted_src, order, att, bias, out, n);
}

// Round 15
// 196.242 us; speedup vs baseline: 1.0571x; 1.0571x over previous
//
#include <hip/hip_runtime.h>
#include <hip/hip_bf16.h>
#include <hip/hip_fp16.h>

typedef _Float16 half8 __attribute__((ext_vector_type(8)));
typedef _Float16 half4_t __attribute__((ext_vector_type(4)));
typedef _Float16 h2 __attribute__((ext_vector_type(2)));
typedef float f32x4 __attribute__((ext_vector_type(4)));
typedef unsigned int u32;

#define NEG_SLOPE 0.2f
#define SELU_SCALE 1.0507009873554805f
#define SELU_ALPHA 1.6732632423543772f
#define LOG2E 1.4426950408889634f
#define DEFER_THR 4.0f

#if __has_builtin(__builtin_amdgcn_fdot2)
#define FDOT2(a, b, c) __builtin_amdgcn_fdot2((a), (b), (c), false)
#else
static __device__ inline float FDOT2(h2 a, h2 b, float c) {
    return c + (float)a[0] * (float)b[0] + (float)a[1] * (float)b[1];
}
#endif

static __device__ inline h2 h2max(h2 a, h2 b) {
#if __has_builtin(__builtin_elementwise_max)
    return __builtin_elementwise_max(a, b);
#else
    h2 r; r[0] = a[0] > b[0] ? a[0] : b[0]; r[1] = a[1] > b[1] ? a[1] : b[1]; return r;
#endif
}

static __device__ inline h2 shfl_h2(h2 v, int d) {
    u32 u = __builtin_bit_cast(u32, v);
    return __builtin_bit_cast(h2, (u32)__shfl_xor((int)u, d, 64));
}

// raw v_exp_f32: D = 2^S0 (flushes to 0 for very negative inputs)
static __device__ inline float fexp2(float x) {
    float r;
    asm("v_exp_f32 %0, %1" : "=v"(r) : "v"(x));
    return r;
}

static __device__ inline h2 pk2(float a) {
#if __has_builtin(__builtin_amdgcn_cvt_pkrtz)
    return __builtin_bit_cast(h2, __builtin_amdgcn_cvt_pkrtz(a, a));
#else
    _Float16 h = (_Float16)a; return (h2){h, h};
#endif
}

// ---------------- dst histogram: 4 edges/thread (int4) ----------------
__global__ __launch_bounds__(256) void hist_kernel(
    const int* __restrict__ eidx, int* __restrict__ count, int n_edges)
{
    int i0 = (blockIdx.x * 256 + threadIdx.x) * 4;
    if (i0 + 3 < n_edges) {
        int4 d4 = *(const int4*)(eidx + (size_t)n_edges + i0);
        atomicAdd(&count[d4.x], 1);
        atomicAdd(&count[d4.y], 1);
        atomicAdd(&count[d4.z], 1);
        atomicAdd(&count[d4.w], 1);
    } else {
        for (int k = 0; k < 4; k++)
            if (i0 + k < n_edges)
                atomicAdd(&count[eidx[(size_t)n_edges + i0 + k]], 1);
    }
}

// local scan of 1024-node chunks (value = deg = count+1) + per-block LDS
// degree histogram (bin = 255 - min(deg,255), i.e. descending degree)
__global__ __launch_bounds__(256) void scan_local_kernel(
    const int* __restrict__ count, int* __restrict__ row_ptr,
    int* __restrict__ blksum, int* __restrict__ blockhist, int n)
{
    __shared__ int ws[4];
    __shared__ int dh[256];
    int blk = blockIdx.x, t = threadIdx.x;
    dh[t] = 0;
    __syncthreads();

    int base = blk * 1024 + t * 4;
    int d0 = (base + 0 < n) ? count[base + 0] + 1 : 0;
    int d1 = (base + 1 < n) ? count[base + 1] + 1 : 0;
    int d2 = (base + 2 < n) ? count[base + 2] + 1 : 0;
    int d3 = (base + 3 < n) ? count[base + 3] + 1 : 0;
    if (d0) atomicAdd(&dh[255 - (d0 < 255 ? d0 : 255)], 1);
    if (d1) atomicAdd(&dh[255 - (d1 < 255 ? d1 : 255)], 1);
    if (d2) atomicAdd(&dh[255 - (d2 < 255 ? d2 : 255)], 1);
    if (d3) atomicAdd(&dh[255 - (d3 < 255 ? d3 : 255)], 1);

    int tsum = d0 + d1 + d2 + d3;
    int lane = t & 63, wid = t >> 6;
    int s = tsum;
    #pragma unroll
    for (int d = 1; d < 64; d <<= 1) {
        int u = __shfl_up(s, d, 64);
        if (lane >= d) s += u;
    }
    if (lane == 63) ws[wid] = s;
    __syncthreads();
    int woff = 0;
    #pragma unroll
    for (int w = 0; w < 4; w++) if (w < wid) woff += ws[w];
    int excl = woff + s - tsum;
    if (base + 0 < n) row_ptr[base + 0] = excl;
    if (base + 1 < n) row_ptr[base + 1] = excl + d0;
    if (base + 2 < n) row_ptr[base + 2] = excl + d0 + d1;
    if (base + 3 < n) row_ptr[base + 3] = excl + d0 + d1 + d2;
    if (t == 255) blksum[blk] = woff + s;
    __syncthreads();
    blockhist[blk * 256 + t] = dh[t];
}

// merged: (a) exclusive scan of blksum (<=64 chunks, wave 0) + total ->
// row_ptr[n]; (b) blockhist -> absolute exclusive offsets per (bin, blk)
__global__ __launch_bounds__(256) void binscan_kernel(
    int* __restrict__ blockhist, int* __restrict__ blksum,
    int* __restrict__ row_ptr, int nblk, int n)
{
    __shared__ int ws[4];
    int b = threadIdx.x;

    if (b < 64) {
        int v = (b < nblk) ? blksum[b] : 0;
        int s = v;
        #pragma unroll
        for (int d = 1; d < 64; d <<= 1) {
            int u = __shfl_up(s, d, 64);
            if (b >= d) s += u;
        }
        if (b < nblk) blksum[b] = s - v;
        if (b == 63) row_ptr[n] = s;
    }

    int vals[64];
    #pragma unroll
    for (int blk = 0; blk < 64; blk++)
        vals[blk] = (blk < nblk) ? blockhist[blk * 256 + b] : 0;
    int run = 0;
    #pragma unroll
    for (int blk = 0; blk < 64; blk++) {
        int x = vals[blk];
        vals[blk] = run;
        run += x;
    }
    int lane = b & 63, wid = b >> 6;
    int s = run;
    #pragma unroll
    for (int d = 1; d < 64; d <<= 1) {
        int u = __shfl_up(s, d, 64);
        if (lane >= d) s += u;
    }
    if (lane == 63) ws[wid] = s;
    __syncthreads();
    int woff = 0;
    #pragma unroll
    for (int w = 0; w < 4; w++) if (w < wid) woff += ws[w];
    int basep = woff + s - run;
    #pragma unroll
    for (int blk = 0; blk < 64; blk++)
        if (blk < nblk) blockhist[blk * 256 + b] = vals[blk] + basep;
}

// fused: finalize row_ptr, init cursor, seed self-loop, counting-sort placement
__global__ __launch_bounds__(256) void cursor_order_kernel(
    int* __restrict__ row_ptr, const int* __restrict__ blksum,
    const int* __restrict__ count, const int* __restrict__ blockhist,
    int* __restrict__ cursor, int* __restrict__ sorted_src,
    int* __restrict__ order, int n)
{
    __shared__ int loff[256];
    int blk = blockIdx.x, t = threadIdx.x;
    loff[t] = blockhist[blk * 256 + t];
    __syncthreads();
    int base = blk * 1024 + t * 4;
    #pragma unroll
    for (int i = 0; i < 4; i++) {
        int node = base + i;
        if (node < n) {
            int rp = row_ptr[node] + blksum[node >> 10];
            row_ptr[node] = rp;
            cursor[node] = rp + 1;       // slot rp reserved for self-loop
            sorted_src[rp] = node;
            int deg = count[node] + 1;
            int bin = 255 - (deg < 255 ? deg : 255);
            int pos = atomicAdd(&loff[bin], 1);
            order[pos] = node;
        }
    }
}

// ---------------- Fused: GEMM (blocks < nbG) + CSR scatter (rest) ----------
// GEMM: glA[n][c]=x@W_l, glB[n][c]=x@W_r (c in [0,384)), 128 rows/block.
// scatter: 4 edges/thread (int4), atomic cursor bump + sorted_src write.
__global__ __launch_bounds__(256) void gemm_scatter_kernel(
    const float* __restrict__ x, const float* __restrict__ Wl,
    const float* __restrict__ Wr, _Float16* __restrict__ glA,
    _Float16* __restrict__ glB, int n_nodes,
    const int* __restrict__ eidx, int* __restrict__ cursor,
    int* __restrict__ sorted_src, int n_edges, int nbG)
{
    __shared__ float xs[128 * 68];
    if ((int)blockIdx.x >= nbG) {
        // ---- scatter part ----
        int i0 = (((int)blockIdx.x - nbG) * 256 + (int)threadIdx.x) * 4;
        if (i0 + 3 < n_edges) {
            int4 s4 = *(const int4*)(eidx + i0);
            int4 d4 = *(const int4*)(eidx + (size_t)n_edges + i0);
            int p0 = atomicAdd(&cursor[d4.x], 1); sorted_src[p0] = s4.x;
            int p1 = atomicAdd(&cursor[d4.y], 1); sorted_src[p1] = s4.y;
            int p2 = atomicAdd(&cursor[d4.z], 1); sorted_src[p2] = s4.z;
            int p3 = atomicAdd(&cursor[d4.w], 1); sorted_src[p3] = s4.w;
        } else {
            for (int k = 0; k < 4; k++) {
                int i = i0 + k;
                if (i < n_edges) {
                    int d = eidx[(size_t)n_edges + i];
                    int s = eidx[i];
                    int pos = atomicAdd(&cursor[d], 1);
                    sorted_src[pos] = s;
                }
            }
        }
        return;
    }

    // ---- GEMM part ----
    int row0 = blockIdx.x * 128;
    if (row0 >= n_nodes) return;
    {
        int t = threadIdx.x;
        #pragma unroll
        for (int i = 0; i < 8; i++) {
            int idx = t + i * 256;           // 2048 float4 total
            int r = idx >> 4, c = (idx & 15) * 4;
            int row = row0 + r;
            f32x4 v = (f32x4){0.f, 0.f, 0.f, 0.f};
            if (row < n_nodes) v = *(const f32x4*)(x + (size_t)row * 64 + c);
            *(f32x4*)(xs + r * 68 + c) = v;
        }
    }
    __syncthreads();

    int wid  = threadIdx.x >> 6;
    int lane = threadIdx.x & 63;
    int l15  = lane & 15;
    int g    = lane >> 4;
    int kb   = g * 8;
    int colbase = wid * 192;

    half8 bw0[12], bw1[12];
    #pragma unroll
    for (int t = 0; t < 12; t++) {
        int col = colbase + t * 16 + l15;
        const float* wcol = (col < 384) ? (Wl + col) : (Wr + (col - 384));
        #pragma unroll
        for (int j = 0; j < 8; j++) {
            bw0[t][j] = (_Float16)wcol[(size_t)(kb + j) * 384];
            bw1[t][j] = (_Float16)wcol[(size_t)(32 + kb + j) * 384];
        }
    }

    #pragma unroll
    for (int rt = 0; rt < 8; rt++) {
        int r0 = rt * 16;
        half8 a0, a1;
        #pragma unroll
        for (int j = 0; j < 8; j++) {
            a0[j] = (_Float16)xs[(r0 + l15) * 68 + kb + j];
            a1[j] = (_Float16)xs[(r0 + l15) * 68 + 32 + kb + j];
        }
        int nodeRow = row0 + r0 + l15;
        #pragma unroll
        for (int t = 0; t < 12; t++) {
            f32x4 acc = (f32x4){0.f, 0.f, 0.f, 0.f};
            acc = __builtin_amdgcn_mfma_f32_16x16x32_f16(bw0[t], a0, acc, 0, 0, 0);
            acc = __builtin_amdgcn_mfma_f32_16x16x32_f16(bw1[t], a1, acc, 0, 0, 0);
            if (nodeRow < n_nodes) {
                int c0 = colbase + t * 16 + g * 4;
                half4_t hv;
                #pragma unroll
                for (int r = 0; r < 4; r++) hv[r] = (_Float16)acc[r];
                _Float16* dst = (c0 < 384)
                    ? (glA + (size_t)nodeRow * 384 + c0)
                    : (glB + (size_t)nodeRow * 384 + (c0 - 384));
                *(half4_t*)dst = hv;
            }
        }
    }
}

// ---------------- Edge phase: 16-lane group per dst node, 1-deep prefetch ----
// Pair-octet layout on 768B rows: lane l0 owns bytes P*256 + l0*16 (P=0..2).
// oct=l0>>3 -> head 2P+oct; q=l0&7 -> f=q*8..q*8+7. 3 heads/lane.
// Nodes processed in descending-degree order (order[]).
__global__ __launch_bounds__(256) void edge_kernel(
    const _Float16* __restrict__ glA,     // [n][384] source-side projection
    const _Float16* __restrict__ glB,     // [n][384] target-side projection
    const int* __restrict__ row_ptr,
    const int* __restrict__ sorted_src,
    const int* __restrict__ order,
    const float* __restrict__ att,        // [6][64]
    const float* __restrict__ bias,       // [64]
    float* __restrict__ out, int n_nodes)
{
    int tid  = blockIdx.x * 256 + threadIdx.x;
    int ggid = tid >> 4;                       // global 16-lane group id
    int GG   = (gridDim.x * 256) >> 4;
    int l0  = threadIdx.x & 15;
    int oct = l0 >> 3;
    int q   = l0 & 7;
    u32 l16 = (u32)l0 * 16u;

    const char* glA_b = (const char*)glA;
    const char* glB_b = (const char*)glB;
    const _Float16 c02 = (_Float16)NEG_SLOPE;

    h2 att_h[12];
    #pragma unroll
    for (int P = 0; P < 3; P++) {
        int h = 2 * P + oct;
        f32x4 av0 = *(const f32x4*)(att + h * 64 + q * 8);
        f32x4 av1 = *(const f32x4*)(att + h * 64 + q * 8 + 4);
        att_h[P * 4 + 0] = (h2){(_Float16)(av0[0] * LOG2E), (_Float16)(av0[1] * LOG2E)};
        att_h[P * 4 + 1] = (h2){(_Float16)(av0[2] * LOG2E), (_Float16)(av0[3] * LOG2E)};
        att_h[P * 4 + 2] = (h2){(_Float16)(av1[0] * LOG2E), (_Float16)(av1[1] * LOG2E)};
        att_h[P * 4 + 3] = (h2){(_Float16)(av1[2] * LOG2E), (_Float16)(av1[3] * LOG2E)};
    }
    f32x4 bv0 = *(const f32x4*)(bias + q * 8);
    f32x4 bv1 = *(const f32x4*)(bias + q * 8 + 4);

    for (int slot = ggid; slot < n_nodes; slot += GG) {
        int node = order[slot];

        h2 gr_h[12];
        {
            u32 rbase = (u32)node * 768u;
            #pragma unroll
            for (int P = 0; P < 3; P++) {
                half8 gv = *(const half8*)(glB_b + rbase + (u32)P * 256u + l16);
                gr_h[P * 4 + 0] = ((h2*)&gv)[0];
                gr_h[P * 4 + 1] = ((h2*)&gv)[1];
                gr_h[P * 4 + 2] = ((h2*)&gv)[2];
                gr_h[P * 4 + 3] = ((h2*)&gv)[3];
            }
        }

        float m[3], sden[3];
        h2 acc[12];
        #pragma unroll
        for (int P = 0; P < 3; P++) { m[P] = -1e30f; sden[P] = 0.f; }
        #pragma unroll
        for (int j = 0; j < 12; j++) acc[j] = (h2){(_Float16)0.f, (_Float16)0.f};

        int rp = row_ptr[node], re = row_ptr[node + 1];
        int reclamp = re - 1;

        auto lsrc = [&](int idx) {
            int ii = idx < reclamp ? idx : reclamp;
            return sorted_src[ii];
        };

        half8 A0, A1, A2, B0, B1, B2;

#define LOADX(X0, X1, X2, S)                                                 \
        {                                                                    \
            u32 o = (u32)(S) * 768u + l16;                                   \
            X0 = *(const half8*)(glA_b + o);                                 \
            X1 = *(const half8*)(glA_b + o + 256);                           \
            X2 = *(const half8*)(glA_b + o + 512);                           \
        }

// defer-max online softmax: rescale only when e exceeds m by > DEFER_THR
#define PROC1(X0, X1, X2)                                                    \
        {                                                                    \
            float e[3];                                                      \
            _Pragma("unroll")                                                \
            for (int P = 0; P < 3; P++) {                                    \
                h2 t0 = ((h2*)&X0)[0], t1 = ((h2*)&X0)[1],                   \
                   t2 = ((h2*)&X0)[2], t3 = ((h2*)&X0)[3];                   \
                if (P == 1) { t0 = ((h2*)&X1)[0]; t1 = ((h2*)&X1)[1];        \
                              t2 = ((h2*)&X1)[2]; t3 = ((h2*)&X1)[3]; }      \
                if (P == 2) { t0 = ((h2*)&X2)[0]; t1 = ((h2*)&X2)[1];        \
                              t2 = ((h2*)&X2)[2]; t3 = ((h2*)&X2)[3]; }      \
                t0 = t0 + gr_h[P * 4 + 0]; t1 = t1 + gr_h[P * 4 + 1];        \
                t2 = t2 + gr_h[P * 4 + 2]; t3 = t3 + gr_h[P * 4 + 3];        \
                t0 = h2max(t0, t0 * c02); t1 = h2max(t1, t1 * c02);          \
                t2 = h2max(t2, t2 * c02); t3 = h2max(t3, t3 * c02);          \
                e[P] = FDOT2(t3, att_h[P * 4 + 3], FDOT2(t2, att_h[P * 4 + 2],\
                       FDOT2(t1, att_h[P * 4 + 1], FDOT2(t0, att_h[P * 4 + 0],\
                       0.f))));                                              \
            }                                                                \
            _Pragma("unroll")                                                \
            for (int d = 1; d < 8; d <<= 1) {                                \
                e[0] += __shfl_xor(e[0], d, 64);                             \
                e[1] += __shfl_xor(e[1], d, 64);                             \
                e[2] += __shfl_xor(e[2], d, 64);                             \
            }                                                                \
            _Pragma("unroll")                                                \
            for (int P = 0; P < 3; P++) {                                    \
                if (e[P] > m[P] + DEFER_THR) {   /* rare rescale path */     \
                    float r = fexp2(m[P] - e[P]);                            \
                    sden[P] *= r;                                            \
                    h2 r2 = pk2(r);                                          \
                    acc[P * 4 + 0] = acc[P * 4 + 0] * r2;                    \
                    acc[P * 4 + 1] = acc[P * 4 + 1] * r2;                    \
                    acc[P * 4 + 2] = acc[P * 4 + 2] * r2;                    \
                    acc[P * 4 + 3] = acc[P * 4 + 3] * r2;                    \
                    m[P] = e[P];                                             \
                }                                                            \
                float p = fexp2(e[P] - m[P]);    /* <= 2^THR */              \
                sden[P] += p;                                                \
                h2 p2 = pk2(p);                                              \
                const h2* xv = (P == 0) ? (const h2*)&X0                     \
                             : (P == 1) ? (const h2*)&X1 : (const h2*)&X2;   \
                acc[P * 4 + 0] = acc[P * 4 + 0] + p2 * xv[0];                \
                acc[P * 4 + 1] = acc[P * 4 + 1] + p2 * xv[1];                \
                acc[P * 4 + 2] = acc[P * 4 + 2] + p2 * xv[2];                \
                acc[P * 4 + 3] = acc[P * 4 + 3] + p2 * xv[3];                \
            }                                                                \
        }

        {   // 1-deep pipeline (A/B alternate)
            LOADX(A0, A1, A2, sorted_src[rp]);
            int sN = lsrc(rp + 1);
            int idx = rp;
            for (;;) {
                LOADX(B0, B1, B2, sN);
                int sN2 = lsrc(idx + 2);
                PROC1(A0, A1, A2);
                idx++; if (idx >= re) break;
                LOADX(A0, A1, A2, sN2);
                sN = lsrc(idx + 2);
                PROC1(B0, B1, B2);
                idx++; if (idx >= re) break;
            }
        }
#undef PROC1
#undef LOADX

        h2 iv[3];
        #pragma unroll
        for (int P = 0; P < 3; P++) {
            float inv = 1.0f / (sden[P] + 1e-16f);
            _Float16 ih = (_Float16)inv;
            iv[P] = (h2){ih, ih};
        }
        float of[8];
        #pragma unroll
        for (int j = 0; j < 4; j++) {
            h2 o = acc[0 * 4 + j] * iv[0] + acc[1 * 4 + j] * iv[1] + acc[2 * 4 + j] * iv[2];
            o = o + shfl_h2(o, 8);       // partner octet: other 3 heads
            of[2 * j]     = (float)o[0];
            of[2 * j + 1] = (float)o[1];
        }

        if (l0 < 8) {                     // oct==0 lanes write the node row
            f32x4 ov0, ov1;
            #pragma unroll
            for (int k = 0; k < 4; k++) {
                float v0 = of[k] * (1.0f / 6.0f) + bv0[k];
                float v1 = of[k + 4] * (1.0f / 6.0f) + bv1[k];
                ov0[k] = (v0 > 0.f) ? SELU_SCALE * v0
                                    : SELU_SCALE * SELU_ALPHA * (__expf(v0) - 1.0f);
                ov1[k] = (v1 > 0.f) ? SELU_SCALE * v1
                                    : SELU_SCALE * SELU_ALPHA * (__expf(v1) - 1.0f);
            }
            float* op = out + (size_t)node * 64 + q * 8;
            *(f32x4*)op = ov0;
            *(f32x4*)(op + 4) = ov1;
        }
    }
}

// ---------------- launch ----------------
extern "C" void kernel_launch(void* const* d_in, const int* in_sizes, int n_in,
                              void* d_out, int out_size, void* d_ws, size_t ws_size,
                              hipStream_t stream) {
    const float* x    = (const float*)d_in[0];
    const int*   eidx = (const int*)d_in[1];
    const float* Wl   = (const float*)d_in[2];
    const float* Wr   = (const float*)d_in[3];
    const float* att  = (const float*)d_in[4];
    const float* bias = (const float*)d_in[5];
    float* out = (float*)d_out;

    int n = in_sizes[0] / 64;        // nodes
    int E = in_sizes[1] / 2;         // edges (pre-self-loop)
    int Et = E + n;
    int nblk = (n + 1023) / 1024;    // 49 for n=50000 (<= 64 required)

    char* w = (char*)d_ws;
    size_t off = 0;
    auto carve = [&](size_t bytes) {
        void* p = w + off;
        off = (off + bytes + 255) & ~(size_t)255;
        return p;
    };
    _Float16* glA   = (_Float16*)carve((size_t)n * 384 * sizeof(_Float16));
    _Float16* glB   = (_Float16*)carve((size_t)n * 384 * sizeof(_Float16));
    int* count      = (int*)carve((size_t)n * sizeof(int));
    int* row_ptr    = (int*)carve((size_t)(n + 1) * sizeof(int));
    int* cursor     = (int*)carve((size_t)n * sizeof(int));
    int* sorted_src = (int*)carve((size_t)Et * sizeof(int));
    int* order      = (int*)carve((size_t)n * sizeof(int));
    int* blksum     = (int*)carve(64 * sizeof(int));
    int* blockhist  = (int*)carve((size_t)nblk * 256 * sizeof(int));
    (void)ws_size;

    int nbG = (n + 127) / 128;                // gemm blocks
    int nbE4 = (E + 1023) / 1024;             // 4-edges/thread blocks

    hipMemsetAsync(count, 0, (size_t)n * sizeof(int), stream);
    hipLaunchKernelGGL(hist_kernel, dim3(nbE4), dim3(256), 0, stream,
                       eidx, count, E);
    hipLaunchKernelGGL(scan_local_kernel, dim3(nblk), dim3(256), 0, stream,
                       count, row_ptr, blksum, blockhist, n);
    hipLaunchKernelGGL(binscan_kernel, dim3(1), dim3(256), 0, stream,
                       blockhist, blksum, row_ptr, nblk, n);
    hipLaunchKernelGGL(cursor_order_kernel, dim3(nblk), dim3(256), 0, stream,
                       row_ptr, blksum, count, blockhist, cursor, sorted_src,
                       order, n);
    hipLaunchKernelGGL(gemm_scatter_kernel, dim3(nbG + nbE4), dim3(256), 0, stream,
                       x, Wl, Wr, glA, glB, n, eidx, cursor, sorted_src, E, nbG);
    hipLaunchKernelGGL(edge_kernel, dim3(2048), dim3(256), 0, stream,
                       glA, glB, row_ptr, sorted_src, order, att, bias, out, n);
}